// Round 15
// baseline (249.085 us; speedup 1.0000x reference)
//
#include <hip/hip_runtime.h>

typedef __bf16 bf16x8 __attribute__((ext_vector_type(8)));
typedef float f32x4 __attribute__((ext_vector_type(4)));
typedef unsigned short u16x8 __attribute__((ext_vector_type(8)));
typedef unsigned short u16x4 __attribute__((ext_vector_type(4)));

__device__ __forceinline__ unsigned short f2bf_bits(float f) {
  unsigned u = __float_as_uint(f);
  return (unsigned short)((u + 0x7FFFu + ((u >> 16) & 1u)) >> 16);
}

__device__ __forceinline__ float exp2_amd(float x) {
  return __builtin_amdgcn_exp2f(x);
}

__device__ __forceinline__ unsigned cvt_pk_bf16(float a, float b) {
  unsigned r;
  asm("v_cvt_pk_bf16_f32 %0, %1, %2" : "=v"(r) : "v"(a), "v"(b));
  return r;
}

// xor16 / xor32 reductions on the VALU pipe (permlane swap) instead of ds_swizzle
__device__ __forceinline__ float red16_max(float x) {
  unsigned a = __float_as_uint(x), b = a;
  asm("v_permlane16_swap_b32 %0, %1" : "+v"(a), "+v"(b));
  return fmaxf(__uint_as_float(a), __uint_as_float(b));
}
__device__ __forceinline__ float red32_max(float x) {
  unsigned a = __float_as_uint(x), b = a;
  asm("v_permlane32_swap_b32 %0, %1" : "+v"(a), "+v"(b));
  return fmaxf(__uint_as_float(a), __uint_as_float(b));
}
__device__ __forceinline__ float red16_sum(float x) {
  unsigned a = __float_as_uint(x), b = a;
  asm("v_permlane16_swap_b32 %0, %1" : "+v"(a), "+v"(b));
  return __uint_as_float(a) + __uint_as_float(b);
}
__device__ __forceinline__ float red32_sum(float x) {
  unsigned a = __float_as_uint(x), b = a;
  asm("v_permlane32_swap_b32 %0, %1" : "+v"(a), "+v"(b));
  return __uint_as_float(a) + __uint_as_float(b);
}

__device__ __forceinline__ void gload16(const void* g, void* l) {
  __builtin_amdgcn_global_load_lds(
      (const __attribute__((address_space(1))) unsigned int*)g,
      (__attribute__((address_space(3))) unsigned int*)l, 16, 0, 0);
}

// ---------------- fused prep: 6 weight transposes + LN1, one dispatch.
// blocks [0,12288): wconv tiles; blocks [12288,16384): LN1 rows.
__global__ __launch_bounds__(256) void prep_k(
    const float* __restrict__ s0, const float* __restrict__ s1,
    const float* __restrict__ s2, const float* __restrict__ s3,
    const float* __restrict__ s4, const float* __restrict__ s5,
    unsigned short* __restrict__ d0, unsigned short* __restrict__ d1,
    unsigned short* __restrict__ d2, unsigned short* __restrict__ d3,
    unsigned short* __restrict__ d4, unsigned short* __restrict__ d5,
    const float* __restrict__ x, const float* __restrict__ g1,
    const float* __restrict__ be1, unsigned short* __restrict__ xn) {
  const int t = blockIdx.x;
  const int tid = threadIdx.x;
  if (t >= 12288) {
    // ---- LN1 row
    const int row = t - 12288;
    const float4 v = ((const float4*)(x + (size_t)row * 1024))[tid];
    float s = v.x + v.y + v.z + v.w;
    float s2 = v.x * v.x + v.y * v.y + v.z * v.z + v.w * v.w;
#pragma unroll
    for (int m = 1; m < 64; m <<= 1) {
      s += __shfl_xor(s, m);
      s2 += __shfl_xor(s2, m);
    }
    __shared__ float red[8];
    const int w = tid >> 6;
    if ((tid & 63) == 0) { red[w] = s; red[4 + w] = s2; }
    __syncthreads();
    s = red[0] + red[1] + red[2] + red[3];
    s2 = red[4] + red[5] + red[6] + red[7];
    const float mu = s * (1.f / 1024.f);
    const float rs_ = rsqrtf(s2 * (1.f / 1024.f) - mu * mu + 1e-5f);
    const float4 gg = ((const float4*)g1)[tid];
    const float4 bb = ((const float4*)be1)[tid];
    u16x4 pack;
    pack.x = f2bf_bits((v.x - mu) * rs_ * gg.x + bb.x);
    pack.y = f2bf_bits((v.y - mu) * rs_ * gg.y + bb.y);
    pack.z = f2bf_bits((v.z - mu) * rs_ * gg.z + bb.z);
    pack.w = f2bf_bits((v.w - mu) * rs_ * gg.w + bb.w);
    *(u16x4*)(xn + (size_t)row * 1024 + tid * 4) = pack;
    return;
  }
  // ---- weight convert+transpose tile
  const float* src;
  unsigned short* dst;
  int R, C, bx, by;
  if (t < 4096) {
    const int i = t >> 10, id = t & 1023;
    src = i == 0 ? s0 : i == 1 ? s1 : i == 2 ? s2 : s3;
    dst = i == 0 ? d0 : i == 1 ? d1 : i == 2 ? d2 : d3;
    R = 1024; C = 1024; bx = id & 31; by = id >> 5;
  } else if (t < 8192) {
    const int id = t - 4096;
    src = s4; dst = d4; R = 1024; C = 4096; bx = id & 127; by = id >> 7;
  } else {
    const int id = t - 8192;
    src = s5; dst = d5; R = 4096; C = 1024; bx = id & 31; by = id >> 5;
  }
  __shared__ float tile[32][33];
  const int tx = tid & 31, ty = tid >> 5;
  const size_t c0 = (size_t)bx * 32, r0 = (size_t)by * 32;
#pragma unroll
  for (int i = 0; i < 4; i++)
    tile[ty + i * 8][tx] = src[(r0 + ty + i * 8) * C + c0 + tx];
  __syncthreads();
#pragma unroll
  for (int i = 0; i < 4; i++) {
    int c = ty + i * 8;
    dst[(c0 + c) * R + r0 + tx] = f2bf_bits(tile[tx][c]);
  }
}

// ---------------- W0 split-K(f32) reduce + residual + LN2 fused:
// x1 = p0 + p1 + b0 + x  (write f32);  xn = LN(x1; g2, be2)  (write bf16)
__global__ __launch_bounds__(256) void w0red_ln(const float* __restrict__ p,
                                                const float* __restrict__ b0,
                                                const float* __restrict__ x,
                                                const float* __restrict__ g,
                                                const float* __restrict__ be,
                                                float* __restrict__ x1f,
                                                unsigned short* __restrict__ xn) {
  const int row = blockIdx.x, tid = threadIdx.x;
  const size_t base = (size_t)row * 1024 + tid * 4;
  const float4 xv = *(const float4*)(x + base);
  const float4 bb0 = ((const float4*)b0)[tid];
  const float4 p0 = *(const float4*)(p + base);
  const float4 p1 = *(const float4*)(p + 4194304 + base);
  float4 v;
  v.x = xv.x + bb0.x + p0.x + p1.x;
  v.y = xv.y + bb0.y + p0.y + p1.y;
  v.z = xv.z + bb0.z + p0.z + p1.z;
  v.w = xv.w + bb0.w + p0.w + p1.w;
  *(float4*)(x1f + base) = v;
  float s = v.x + v.y + v.z + v.w;
  float s2 = v.x * v.x + v.y * v.y + v.z * v.z + v.w * v.w;
#pragma unroll
  for (int m = 1; m < 64; m <<= 1) {
    s += __shfl_xor(s, m);
    s2 += __shfl_xor(s2, m);
  }
  __shared__ float red[8];
  const int w = tid >> 6;
  if ((tid & 63) == 0) { red[w] = s; red[4 + w] = s2; }
  __syncthreads();
  s = red[0] + red[1] + red[2] + red[3];
  s2 = red[4] + red[5] + red[6] + red[7];
  const float mu = s * (1.f / 1024.f);
  const float rs_ = rsqrtf(s2 * (1.f / 1024.f) - mu * mu + 1e-5f);
  const float4 gg = ((const float4*)g)[tid];
  const float4 bb = ((const float4*)be)[tid];
  u16x4 pack;
  pack.x = f2bf_bits((v.x - mu) * rs_ * gg.x + bb.x);
  pack.y = f2bf_bits((v.y - mu) * rs_ * gg.y + bb.y);
  pack.z = f2bf_bits((v.z - mu) * rs_ * gg.z + bb.z);
  pack.w = f2bf_bits((v.w - mu) * rs_ * gg.w + bb.w);
  *(u16x4*)(xn + base) = pack;
}

// ---------------- split-K reduce for FF2: out = p0 + p1 + bias + res (all f32)
__global__ __launch_bounds__(256) void ff2red(const float* __restrict__ p,
                                              const float* __restrict__ bias,
                                              const float* __restrict__ res,
                                              float* __restrict__ out) {
  const size_t i = ((size_t)blockIdx.x * 256 + threadIdx.x) * 8;
  const int col = (int)(i & 1023);
  const float4 b0 = *(const float4*)(bias + col);
  const float4 b1 = *(const float4*)(bias + col + 4);
  const float4 r0 = *(const float4*)(res + i);
  const float4 r1 = *(const float4*)(res + i + 4);
  const float4 p00 = *(const float4*)(p + i);
  const float4 p01 = *(const float4*)(p + i + 4);
  const float4 p10 = *(const float4*)(p + 4194304 + i);
  const float4 p11 = *(const float4*)(p + 4194304 + i + 4);
  float4 o0 = {b0.x + r0.x + p00.x + p10.x, b0.y + r0.y + p00.y + p10.y,
               b0.z + r0.z + p00.z + p10.z, b0.w + r0.w + p00.w + p10.w};
  float4 o1 = {b1.x + r1.x + p01.x + p11.x, b1.y + r1.y + p01.y + p11.y,
               b1.z + r1.z + p01.z + p11.z, b1.w + r1.w + p01.w + p11.w};
  *(float4*)(out + i) = o0;
  *(float4*)(out + i + 4) = o1;
}

// ---------------- GEMM: C[M][N] = epi(A[M][K(row stride)] @ Bt[N][K]^T ...)
// EPI 0: bf16 store. 2: +bias, relu, bf16 store. 3: f32 PARTIAL store at z-slice.
// Counted-vmcnt double-buffered pipeline (T3/T4) + XCD swizzle (T1) + setprio (T5).
template <int EPI>
__global__ __launch_bounds__(256) void gemm_bt(
    const unsigned short* __restrict__ A, const unsigned short* __restrict__ Bt,
    const float* __restrict__ bias, const float* __restrict__ res,
    void* __restrict__ Cv, int M, int N, int K, int KL) {
  __shared__ __align__(16) unsigned short As[2][128 * 64];
  __shared__ __align__(16) unsigned short Bs[2][128 * 64];
  const int tid = threadIdx.x, lane = tid & 63, w = tid >> 6;
  const int lo = lane & 15, hi = lane >> 4;
  const int l8 = lane >> 3, l7 = lane & 7;
  const int scol = ((l7 ^ l8) << 3);  // swizzled source col (elements)
  const int nwg = gridDim.x * gridDim.y;
  int bid = blockIdx.y * gridDim.x + blockIdx.x;
  if ((nwg & 7) == 0) bid = (bid & 7) * (nwg >> 3) + (bid >> 3);
  const int bx = bid % gridDim.x, by = bid / gridDim.x;
  const size_t rowBase = (size_t)by * 128;
  const size_t colBase = (size_t)bx * 128;
  const int kOff = blockIdx.z * KL;
  f32x4 acc[4][4];
#pragma unroll
  for (int i = 0; i < 4; i++)
#pragma unroll
    for (int j = 0; j < 4; j++) acc[i][j] = (f32x4){0.f, 0.f, 0.f, 0.f};
  const int wr = (w >> 1) * 64, wc = (w & 1) * 64;
  const unsigned short* aSrc = A + (rowBase + (size_t)w * 32 + l8) * K + scol + kOff;
  const unsigned short* bSrc = Bt + (colBase + (size_t)w * 32 + l8) * K + scol + kOff;

  const int NT = KL >> 6;
  auto stage = [&](int t, int buf) {
    const int kb = t << 6;
#pragma unroll
    for (int c = 0; c < 4; c++) {
      gload16(aSrc + (size_t)c * 8 * K + kb, &As[buf][(w * 4 + c) * 512]);
      gload16(bSrc + (size_t)c * 8 * K + kb, &Bs[buf][(w * 4 + c) * 512]);
    }
  };

  stage(0, 0);
  stage(1, 1);
  asm volatile("s_waitcnt vmcnt(8)" ::: "memory");
  __builtin_amdgcn_s_barrier();

  for (int t = 0; t < NT; ++t) {
    const int cur = t & 1;
    const char* asb = (const char*)As[cur];
    const char* bsb = (const char*)Bs[cur];
    __builtin_amdgcn_s_setprio(1);
#pragma unroll
    for (int ks = 0; ks < 2; ks++) {
      bf16x8 af[4], bfr[4];
      const int kbyte = ks * 64 + (hi << 4);
#pragma unroll
      for (int i = 0; i < 4; i++) {
        const int ar = wr + i * 16 + lo;
        af[i] = *(const bf16x8*)(asb + ar * 128 + (kbyte ^ ((ar & 7) << 4)));
        const int br = wc + i * 16 + lo;
        bfr[i] = *(const bf16x8*)(bsb + br * 128 + (kbyte ^ ((br & 7) << 4)));
      }
#pragma unroll
      for (int i = 0; i < 4; i++)
#pragma unroll
        for (int j = 0; j < 4; j++)
          acc[i][j] = __builtin_amdgcn_mfma_f32_16x16x32_bf16(af[i], bfr[j], acc[i][j], 0, 0, 0);
    }
    __builtin_amdgcn_s_setprio(0);
    asm volatile("s_waitcnt lgkmcnt(0)" ::: "memory");
    __builtin_amdgcn_s_barrier();  // B1: everyone done reading buf[cur]
    if (t + 2 < NT) {
      stage(t + 2, cur);
      asm volatile("s_waitcnt vmcnt(8)" ::: "memory");
    } else {
      asm volatile("s_waitcnt vmcnt(0)" ::: "memory");
    }
    __builtin_amdgcn_s_barrier();  // B2: buf[cur^1] fully staged for all waves
  }

  const size_t zOff = (size_t)blockIdx.z * M * N;
#pragma unroll
  for (int i = 0; i < 4; i++) {
#pragma unroll
    for (int r = 0; r < 4; r++) {
      const size_t row = rowBase + wr + i * 16 + hi * 4 + r;
#pragma unroll
      for (int j = 0; j < 4; j++) {
        const size_t col = colBase + wc + j * 16 + lo;
        float v = acc[i][j][r];
        if (EPI == 2) {
          ((unsigned short*)Cv)[row * N + col] = f2bf_bits(fmaxf(v + bias[col], 0.f));
        } else if (EPI == 3) {
          ((float*)Cv)[zOff + row * N + col] = v;
        } else {
          ((unsigned short*)Cv)[row * N + col] = f2bf_bits(v);
        }
      }
    }
  }
}

// ---------------- flash attention: grid 512 = (qt, h, n) with XCD-L2 clustering.
// QBLK=128 (4 waves x 32 q-rows, two 16-q groups sharing K/V LDS reads),
// KVBLK=128 (16 iterations). Double-buffered Ks/Vt, one __syncthreads per iter.
// Swapped QK^T (T12); softmax lane-local; P->PV via cvt_pk + permlane32_swap.
__global__ __launch_bounds__(256) void attn_k(const unsigned short* __restrict__ Q,
                                              const unsigned short* __restrict__ K,
                                              const unsigned short* __restrict__ V,
                                              unsigned short* __restrict__ O) {
  __shared__ __align__(16) unsigned short Ks[2][128 * 64];
  __shared__ __align__(16) unsigned short Vt[2][64 * 128];  // Vt[d][kv] (swizzled)
  const int tid = threadIdx.x, lane = tid & 63, w = tid >> 6;
  const int lo = lane & 15, hi = lane >> 4;
  const int l8 = lane >> 3, l7 = lane & 7;
  const int scol = ((l7 ^ l8) << 3);
  // XCD-L2 clustering: xcd = b%8 fixed per (h,n) group of 4; qt = b>>5 in [0,16)
  const int b = blockIdx.x;
  const int qt = b >> 5;
  const int hn = (b & 7) + 8 * ((b >> 3) & 3);
  const int h = hn & 15, n = hn >> 4;
  const size_t tRow0 = (size_t)n * 2048;
  const int colBase = h * 64;
  const int LD = 3072;
  const float SC = 0.125f * 1.44269504f;  // (1/sqrt(64)) * log2(e)

  // Q fragments for two q-groups: qa = qt*128 + w*32 + lo, qb = qa + 16
  const unsigned short* qrowA = Q + (tRow0 + qt * 128 + w * 32 + lo) * LD + colBase;
  const unsigned short* qrowB = qrowA + 16 * LD;
  const bf16x8 qf[2][2] = {
      {*(const bf16x8*)(qrowA + hi * 8), *(const bf16x8*)(qrowA + 32 + hi * 8)},
      {*(const bf16x8*)(qrowB + hi * 8), *(const bf16x8*)(qrowB + 32 + hi * 8)}};
  float m2[2] = {-1e30f, -1e30f}, l_r[2] = {0.f, 0.f};
  f32x4 oacc[2][4];
#pragma unroll
  for (int g = 0; g < 2; g++)
#pragma unroll
    for (int d = 0; d < 4; d++) oacc[g][d] = (f32x4){0.f, 0.f, 0.f, 0.f};

  // per-thread V staging coords: thread owns kv row vkv, d-range [vdg*32, vdg*32+32)
  const int vkv = tid & 127, vdg = tid >> 7;
  const unsigned short* vbase = V + (tRow0 + vkv) * LD + colBase + vdg * 32;
  // per-thread K staging base: wave w owns rows w*32 .. w*32+31 (4 chunks of 8)
  const unsigned short* kbase = K + (tRow0 + (size_t)w * 32 + l8) * LD + colBase + scol;

  // conflict-free b16 scatter into Vt[d][kv] (row stride 256B), swizzle j<<4
  auto vwrite = [&](char* vt, u16x8 a0, u16x8 a1, u16x8 a2, u16x8 a3) {
#pragma unroll
    for (int j = 0; j < 8; j++) {
      const int d0 = vdg * 32 + j;
      const int sw = ((vkv * 2) ^ (j << 4));
      *(unsigned short*)(vt + d0 * 256 + sw) = a0[j];
      *(unsigned short*)(vt + (d0 + 8) * 256 + sw) = a1[j];
      *(unsigned short*)(vt + (d0 + 16) * 256 + sw) = a2[j];
      *(unsigned short*)(vt + (d0 + 24) * 256 + sw) = a3[j];
    }
  };

  // ---- prologue: stage tile 0 into buffer 0
  u16x8 v0 = *(const u16x8*)(vbase);
  u16x8 v1 = *(const u16x8*)(vbase + 8);
  u16x8 v2 = *(const u16x8*)(vbase + 16);
  u16x8 v3 = *(const u16x8*)(vbase + 24);
#pragma unroll
  for (int c = 0; c < 4; c++)
    gload16(kbase + (size_t)c * 8 * LD, &Ks[0][(w * 4 + c) * 512]);
  vwrite((char*)Vt[0], v0, v1, v2, v3);
  __syncthreads();

  for (int t = 0; t < 16; ++t) {
    const int cur = t & 1;
    // ---- issue next-tile loads early (hide under compute)
    if (t < 15) {
      const unsigned short* vs = vbase + (size_t)(t + 1) * 128 * LD;
      v0 = *(const u16x8*)(vs);
      v1 = *(const u16x8*)(vs + 8);
      v2 = *(const u16x8*)(vs + 16);
      v3 = *(const u16x8*)(vs + 24);
#pragma unroll
      for (int c = 0; c < 4; c++)
        gload16(kbase + ((size_t)(t + 1) * 128 + c * 8) * LD, &Ks[cur ^ 1][(w * 4 + c) * 512]);
    }
    // ---- swapped QK^T from Ks[cur]: s[g][f][r] = P[kv=f*16+hi*4+r][q]
    f32x4 s[2][8];
    const char* ksb = (const char*)Ks[cur];
    __builtin_amdgcn_s_setprio(1);
#pragma unroll
    for (int f = 0; f < 8; f++) {
      const int kr = f * 16 + lo;
      const bf16x8 b0 = *(const bf16x8*)(ksb + kr * 128 + ((hi * 16) ^ ((kr & 7) << 4)));
      const bf16x8 b1 = *(const bf16x8*)(ksb + kr * 128 + ((64 + hi * 16) ^ ((kr & 7) << 4)));
#pragma unroll
      for (int g = 0; g < 2; g++) {
        s[g][f] = __builtin_amdgcn_mfma_f32_16x16x32_bf16(b0, qf[g][0], (f32x4){0.f, 0.f, 0.f, 0.f}, 0, 0, 0);
        s[g][f] = __builtin_amdgcn_mfma_f32_16x16x32_bf16(b1, qf[g][1], s[g][f], 0, 0, 0);
      }
    }
    __builtin_amdgcn_s_setprio(0);
    // ---- softmax per q-group, lane-local for q (32 kv values per lane)
    unsigned W2[2][8][2];
#pragma unroll
    for (int g = 0; g < 2; g++) {
      float mx = -1e30f;
#pragma unroll
      for (int f = 0; f < 8; f++)
        mx = fmaxf(mx, fmaxf(fmaxf(s[g][f][0], s[g][f][1]), fmaxf(s[g][f][2], s[g][f][3])));
      mx = red16_max(mx);
      mx = red32_max(mx);
      const float mx2v = mx * SC;
      if (__any(mx2v > m2[g] + 8.f)) {  // defer-max (T13)
        const float mn = fmaxf(m2[g], mx2v);
        const float al = exp2_amd(m2[g] - mn);
        l_r[g] *= al;
        m2[g] = mn;
#pragma unroll
        for (int r = 0; r < 4; r++) {
          const float alr = __shfl(al, hi * 4 + r);
#pragma unroll
          for (int d = 0; d < 4; d++) oacc[g][d][r] *= alr;
        }
      }
      float lsum = 0.f;
#pragma unroll
      for (int f = 0; f < 8; f++) {
        float p0 = exp2_amd(fmaf(s[g][f][0], SC, -m2[g]));
        float p1 = exp2_amd(fmaf(s[g][f][1], SC, -m2[g]));
        float p2 = exp2_amd(fmaf(s[g][f][2], SC, -m2[g]));
        float p3 = exp2_amd(fmaf(s[g][f][3], SC, -m2[g]));
        lsum += (p0 + p1) + (p2 + p3);
        W2[g][f][0] = cvt_pk_bf16(p0, p1);
        W2[g][f][1] = cvt_pk_bf16(p2, p3);
      }
      l_r[g] += lsum;
    }
    // ---- redistribute P to A-fragment layout + PV (V frags shared by groups)
    __builtin_amdgcn_s_setprio(1);
#pragma unroll
    for (int ks = 0; ks < 4; ks++) {
      union { unsigned u[4]; bf16x8 v; } apu[2];
#pragma unroll
      for (int g = 0; g < 2; g++) {
        unsigned wa[2], wb[2];
#pragma unroll
        for (int hh = 0; hh < 2; hh++) {
          unsigned X = W2[g][ks * 2][hh], Y = W2[g][ks * 2 + 1][hh];
          asm("v_permlane32_swap_b32 %0, %1" : "+v"(X), "+v"(Y));
          const unsigned Bx = __shfl_xor((int)Y, 16);
          const unsigned Ax = __shfl_xor((int)X, 16);
          wa[hh] = (hi & 1) ? Bx : X;
          wb[hh] = (hi & 1) ? Y : Ax;
        }
        apu[g].u[0] = wa[0]; apu[g].u[1] = wa[1]; apu[g].u[2] = wb[0]; apu[g].u[3] = wb[1];
      }
      const int kbyte = ks * 64 + (hi << 4);
#pragma unroll
      for (int d = 0; d < 4; d++) {
        const int dr = d * 16 + lo;
        const bf16x8 bv = *(const bf16x8*)((const char*)Vt[cur] + dr * 256 + (kbyte ^ ((dr & 7) << 4)));
        oacc[0][d] = __builtin_amdgcn_mfma_f32_16x16x32_bf16(apu[0].v, bv, oacc[0][d], 0, 0, 0);
        oacc[1][d] = __builtin_amdgcn_mfma_f32_16x16x32_bf16(apu[1].v, bv, oacc[1][d], 0, 0, 0);
      }
    }
    __builtin_amdgcn_s_setprio(0);
    // ---- write next V tile into the other buffer (reg staging arrived by now)
    if (t < 15) vwrite((char*)Vt[cur ^ 1], v0, v1, v2, v3);
    __syncthreads();  // staging of next tile complete; cur reads done
  }
  // ---- epilogue per q-group: reduce l across hi-groups (q), store
#pragma unroll
  for (int g = 0; g < 2; g++) {
    const float l = red32_sum(red16_sum(l_r[g]));
    const float inv = 1.f / l;
#pragma unroll
    for (int r = 0; r < 4; r++) {
      const float invr = __shfl(inv, hi * 4 + r);
      const size_t row = tRow0 + qt * 128 + w * 32 + g * 16 + hi * 4 + r;
#pragma unroll
      for (int d = 0; d < 4; d++)
        O[row * 1024 + colBase + d * 16 + lo] = f2bf_bits(oacc[g][d][r] * invr);
    }
  }
}

extern "C" void kernel_launch(void* const* d_in, const int* in_sizes, int n_in,
                              void* d_out, int out_size, void* d_ws, size_t ws_size,
                              hipStream_t stream) {
  (void)in_sizes; (void)n_in; (void)out_size; (void)ws_size;
  const float* x   = (const float*)d_in[0];
  const float* w_q = (const float*)d_in[2];
  const float* w_k = (const float*)d_in[3];
  const float* w_v = (const float*)d_in[4];
  const float* w_0 = (const float*)d_in[5];
  const float* b_0 = (const float*)d_in[6];
  const float* w_1 = (const float*)d_in[7];
  const float* b_1 = (const float*)d_in[8];
  const float* w_2 = (const float*)d_in[9];
  const float* b_2 = (const float*)d_in[10];
  const float* g_1 = (const float*)d_in[11];
  const float* be_1 = (const float*)d_in[12];
  const float* g_2 = (const float*)d_in[13];
  const float* be_2 = (const float*)d_in[14];

  char* ws = (char*)d_ws;
  size_t off = 0;
  auto alloc = [&](size_t bytes) {
    void* p = ws + off;
    off += (bytes + 255) & ~(size_t)255;
    return p;
  };
  const size_t MB = 1024 * 1024;
  unsigned short* wt_q = (unsigned short*)alloc(2 * MB);
  unsigned short* wt_k = (unsigned short*)alloc(2 * MB);
  unsigned short* wt_v = (unsigned short*)alloc(2 * MB);
  unsigned short* wt_0 = (unsigned short*)alloc(2 * MB);
  unsigned short* wt_1 = (unsigned short*)alloc(8 * MB);   // [4096][1024]
  unsigned short* wt_2 = (unsigned short*)alloc(8 * MB);   // [1024][4096]
  unsigned short* xn   = (unsigned short*)alloc(8 * MB);   // [4096][1024]
  unsigned short* qkv  = (unsigned short*)alloc(24 * MB);  // [4096][3072]
  unsigned short* aO   = (unsigned short*)alloc(8 * MB);
  float*          x1f  = (float*)alloc(16 * MB);           // [4096][1024] f32
  unsigned short* ff1  = (unsigned short*)alloc(32 * MB);  // [4096][4096]
  // scratch reuse (regions dead at time of use):
  float* w0part  = (float*)ff1;   // 2 x 16MB f32 W0 partials (ff1 dead until FF1)
  float* ff2part = (float*)qkv;   // 2 x 16MB f32 FF2 partials (qkv+aO dead by FF2)

  // fused: 6 weight transposes + LN1 in one dispatch
  prep_k<<<16384, 256, 0, stream>>>(w_q, w_k, w_v, w_0, w_1, w_2,
                                    wt_q, wt_k, wt_v, wt_0, wt_1, wt_2,
                                    x, g_1, be_1, xn);
  // fused QKV projection: [4096][1024] @ [3072][1024]^T -> [4096][3072]
  gemm_bt<0><<<dim3(24, 32), 256, 0, stream>>>(xn, wt_q, nullptr, nullptr, qkv, 4096, 3072, 1024, 1024);
  // attention (Q/K/V columns of the fused buffer, row stride 3072)
  attn_k<<<512, 256, 0, stream>>>(qkv, qkv + 1024, qkv + 2048, aO);
  // W0 split-K=2 -> f32 partials (into ff1 scratch), then fused reduce+residual+LN2
  gemm_bt<3><<<dim3(8, 32, 2), 256, 0, stream>>>(aO, wt_0, nullptr, nullptr, w0part, 4096, 1024, 1024, 512);
  w0red_ln<<<4096, 256, 0, stream>>>(w0part, b_0, x, g_2, be_2, x1f, xn);
  // FF1 + relu (overwrites w0part scratch)
  gemm_bt<2><<<dim3(32, 32), 256, 0, stream>>>(xn, wt_1, b_1, nullptr, ff1, 4096, 4096, 1024, 1024);
  // FF2 split-K=2 -> f32 partials, then fused reduce (+bias +residual) -> out f32
  gemm_bt<3><<<dim3(8, 32, 2), 256, 0, stream>>>(ff1, wt_2, nullptr, nullptr, ff2part, 4096, 1024, 4096, 2048);
  ff2red<<<2048, 256, 0, stream>>>(ff2part, b_2, x1f, (float*)d_out);
}

// Round 16
// 244.403 us; speedup vs baseline: 1.0192x; 1.0192x over previous
//
#include <hip/hip_runtime.h>

typedef __bf16 bf16x8 __attribute__((ext_vector_type(8)));
typedef float f32x4 __attribute__((ext_vector_type(4)));
typedef unsigned short u16x8 __attribute__((ext_vector_type(8)));
typedef unsigned short u16x4 __attribute__((ext_vector_type(4)));

__device__ __forceinline__ unsigned short f2bf_bits(float f) {
  unsigned u = __float_as_uint(f);
  return (unsigned short)((u + 0x7FFFu + ((u >> 16) & 1u)) >> 16);
}

__device__ __forceinline__ float exp2_amd(float x) {
  return __builtin_amdgcn_exp2f(x);
}

__device__ __forceinline__ unsigned cvt_pk_bf16(float a, float b) {
  unsigned r;
  asm("v_cvt_pk_bf16_f32 %0, %1, %2" : "=v"(r) : "v"(a), "v"(b));
  return r;
}

// xor16 / xor32 reductions on the VALU pipe (permlane swap) instead of ds_swizzle
__device__ __forceinline__ float red16_max(float x) {
  unsigned a = __float_as_uint(x), b = a;
  asm("v_permlane16_swap_b32 %0, %1" : "+v"(a), "+v"(b));
  return fmaxf(__uint_as_float(a), __uint_as_float(b));
}
__device__ __forceinline__ float red32_max(float x) {
  unsigned a = __float_as_uint(x), b = a;
  asm("v_permlane32_swap_b32 %0, %1" : "+v"(a), "+v"(b));
  return fmaxf(__uint_as_float(a), __uint_as_float(b));
}
__device__ __forceinline__ float red16_sum(float x) {
  unsigned a = __float_as_uint(x), b = a;
  asm("v_permlane16_swap_b32 %0, %1" : "+v"(a), "+v"(b));
  return __uint_as_float(a) + __uint_as_float(b);
}
__device__ __forceinline__ float red32_sum(float x) {
  unsigned a = __float_as_uint(x), b = a;
  asm("v_permlane32_swap_b32 %0, %1" : "+v"(a), "+v"(b));
  return __uint_as_float(a) + __uint_as_float(b);
}

__device__ __forceinline__ void gload16(const void* g, void* l) {
  __builtin_amdgcn_global_load_lds(
      (const __attribute__((address_space(1))) unsigned int*)g,
      (__attribute__((address_space(3))) unsigned int*)l, 16, 0, 0);
}

// ---------------- fused prep: 6 weight transposes + LN1, one dispatch.
// blocks [0,12288): wconv tiles; blocks [12288,16384): LN1 rows.
__global__ __launch_bounds__(256) void prep_k(
    const float* __restrict__ s0, const float* __restrict__ s1,
    const float* __restrict__ s2, const float* __restrict__ s3,
    const float* __restrict__ s4, const float* __restrict__ s5,
    unsigned short* __restrict__ d0, unsigned short* __restrict__ d1,
    unsigned short* __restrict__ d2, unsigned short* __restrict__ d3,
    unsigned short* __restrict__ d4, unsigned short* __restrict__ d5,
    const float* __restrict__ x, const float* __restrict__ g1,
    const float* __restrict__ be1, unsigned short* __restrict__ xn) {
  const int t = blockIdx.x;
  const int tid = threadIdx.x;
  if (t >= 12288) {
    // ---- LN1 row
    const int row = t - 12288;
    const float4 v = ((const float4*)(x + (size_t)row * 1024))[tid];
    float s = v.x + v.y + v.z + v.w;
    float s2 = v.x * v.x + v.y * v.y + v.z * v.z + v.w * v.w;
#pragma unroll
    for (int m = 1; m < 64; m <<= 1) {
      s += __shfl_xor(s, m);
      s2 += __shfl_xor(s2, m);
    }
    __shared__ float red[8];
    const int w = tid >> 6;
    if ((tid & 63) == 0) { red[w] = s; red[4 + w] = s2; }
    __syncthreads();
    s = red[0] + red[1] + red[2] + red[3];
    s2 = red[4] + red[5] + red[6] + red[7];
    const float mu = s * (1.f / 1024.f);
    const float rs_ = rsqrtf(s2 * (1.f / 1024.f) - mu * mu + 1e-5f);
    const float4 gg = ((const float4*)g1)[tid];
    const float4 bb = ((const float4*)be1)[tid];
    u16x4 pack;
    pack.x = f2bf_bits((v.x - mu) * rs_ * gg.x + bb.x);
    pack.y = f2bf_bits((v.y - mu) * rs_ * gg.y + bb.y);
    pack.z = f2bf_bits((v.z - mu) * rs_ * gg.z + bb.z);
    pack.w = f2bf_bits((v.w - mu) * rs_ * gg.w + bb.w);
    *(u16x4*)(xn + (size_t)row * 1024 + tid * 4) = pack;
    return;
  }
  // ---- weight convert+transpose tile
  const float* src;
  unsigned short* dst;
  int R, C, bx, by;
  if (t < 4096) {
    const int i = t >> 10, id = t & 1023;
    src = i == 0 ? s0 : i == 1 ? s1 : i == 2 ? s2 : s3;
    dst = i == 0 ? d0 : i == 1 ? d1 : i == 2 ? d2 : d3;
    R = 1024; C = 1024; bx = id & 31; by = id >> 5;
  } else if (t < 8192) {
    const int id = t - 4096;
    src = s4; dst = d4; R = 1024; C = 4096; bx = id & 127; by = id >> 7;
  } else {
    const int id = t - 8192;
    src = s5; dst = d5; R = 4096; C = 1024; bx = id & 31; by = id >> 5;
  }
  __shared__ float tile[32][33];
  const int tx = tid & 31, ty = tid >> 5;
  const size_t c0 = (size_t)bx * 32, r0 = (size_t)by * 32;
#pragma unroll
  for (int i = 0; i < 4; i++)
    tile[ty + i * 8][tx] = src[(r0 + ty + i * 8) * C + c0 + tx];
  __syncthreads();
#pragma unroll
  for (int i = 0; i < 4; i++) {
    int c = ty + i * 8;
    dst[(c0 + c) * R + r0 + tx] = f2bf_bits(tile[tx][c]);
  }
}

// ---------------- W0 split-K(f32) reduce + residual + LN2 fused:
// x1 = p0 + p1 + b0 + x  (write f32);  xn = LN(x1; g2, be2)  (write bf16)
__global__ __launch_bounds__(256) void w0red_ln(const float* __restrict__ p,
                                                const float* __restrict__ b0,
                                                const float* __restrict__ x,
                                                const float* __restrict__ g,
                                                const float* __restrict__ be,
                                                float* __restrict__ x1f,
                                                unsigned short* __restrict__ xn) {
  const int row = blockIdx.x, tid = threadIdx.x;
  const size_t base = (size_t)row * 1024 + tid * 4;
  const float4 xv = *(const float4*)(x + base);
  const float4 bb0 = ((const float4*)b0)[tid];
  const float4 p0 = *(const float4*)(p + base);
  const float4 p1 = *(const float4*)(p + 4194304 + base);
  float4 v;
  v.x = xv.x + bb0.x + p0.x + p1.x;
  v.y = xv.y + bb0.y + p0.y + p1.y;
  v.z = xv.z + bb0.z + p0.z + p1.z;
  v.w = xv.w + bb0.w + p0.w + p1.w;
  *(float4*)(x1f + base) = v;
  float s = v.x + v.y + v.z + v.w;
  float s2 = v.x * v.x + v.y * v.y + v.z * v.z + v.w * v.w;
#pragma unroll
  for (int m = 1; m < 64; m <<= 1) {
    s += __shfl_xor(s, m);
    s2 += __shfl_xor(s2, m);
  }
  __shared__ float red[8];
  const int w = tid >> 6;
  if ((tid & 63) == 0) { red[w] = s; red[4 + w] = s2; }
  __syncthreads();
  s = red[0] + red[1] + red[2] + red[3];
  s2 = red[4] + red[5] + red[6] + red[7];
  const float mu = s * (1.f / 1024.f);
  const float rs_ = rsqrtf(s2 * (1.f / 1024.f) - mu * mu + 1e-5f);
  const float4 gg = ((const float4*)g)[tid];
  const float4 bb = ((const float4*)be)[tid];
  u16x4 pack;
  pack.x = f2bf_bits((v.x - mu) * rs_ * gg.x + bb.x);
  pack.y = f2bf_bits((v.y - mu) * rs_ * gg.y + bb.y);
  pack.z = f2bf_bits((v.z - mu) * rs_ * gg.z + bb.z);
  pack.w = f2bf_bits((v.w - mu) * rs_ * gg.w + bb.w);
  *(u16x4*)(xn + base) = pack;
}

// ---------------- split-K reduce for FF2: out = p0 + p1 + bias + res (all f32)
__global__ __launch_bounds__(256) void ff2red(const float* __restrict__ p,
                                              const float* __restrict__ bias,
                                              const float* __restrict__ res,
                                              float* __restrict__ out) {
  const size_t i = ((size_t)blockIdx.x * 256 + threadIdx.x) * 8;
  const int col = (int)(i & 1023);
  const float4 b0 = *(const float4*)(bias + col);
  const float4 b1 = *(const float4*)(bias + col + 4);
  const float4 r0 = *(const float4*)(res + i);
  const float4 r1 = *(const float4*)(res + i + 4);
  const float4 p00 = *(const float4*)(p + i);
  const float4 p01 = *(const float4*)(p + i + 4);
  const float4 p10 = *(const float4*)(p + 4194304 + i);
  const float4 p11 = *(const float4*)(p + 4194304 + i + 4);
  float4 o0 = {b0.x + r0.x + p00.x + p10.x, b0.y + r0.y + p00.y + p10.y,
               b0.z + r0.z + p00.z + p10.z, b0.w + r0.w + p00.w + p10.w};
  float4 o1 = {b1.x + r1.x + p01.x + p11.x, b1.y + r1.y + p01.y + p11.y,
               b1.z + r1.z + p01.z + p11.z, b1.w + r1.w + p01.w + p11.w};
  *(float4*)(out + i) = o0;
  *(float4*)(out + i + 4) = o1;
}

// ---------------- GEMM: C[M][N] = epi(A[M][K(row stride)] @ Bt[N][K]^T ...)
// EPI 0: bf16 store. 2: +bias, relu, bf16 store. 3: f32 PARTIAL store at z-slice.
// Counted-vmcnt double-buffered pipeline (T3/T4) + XCD swizzle (T1) + setprio (T5).
template <int EPI>
__global__ __launch_bounds__(256) void gemm_bt(
    const unsigned short* __restrict__ A, const unsigned short* __restrict__ Bt,
    const float* __restrict__ bias, const float* __restrict__ res,
    void* __restrict__ Cv, int M, int N, int K, int KL) {
  __shared__ __align__(16) unsigned short As[2][128 * 64];
  __shared__ __align__(16) unsigned short Bs[2][128 * 64];
  const int tid = threadIdx.x, lane = tid & 63, w = tid >> 6;
  const int lo = lane & 15, hi = lane >> 4;
  const int l8 = lane >> 3, l7 = lane & 7;
  const int scol = ((l7 ^ l8) << 3);  // swizzled source col (elements)
  const int nwg = gridDim.x * gridDim.y;
  int bid = blockIdx.y * gridDim.x + blockIdx.x;
  if ((nwg & 7) == 0) bid = (bid & 7) * (nwg >> 3) + (bid >> 3);
  const int bx = bid % gridDim.x, by = bid / gridDim.x;
  const size_t rowBase = (size_t)by * 128;
  const size_t colBase = (size_t)bx * 128;
  const int kOff = blockIdx.z * KL;
  f32x4 acc[4][4];
#pragma unroll
  for (int i = 0; i < 4; i++)
#pragma unroll
    for (int j = 0; j < 4; j++) acc[i][j] = (f32x4){0.f, 0.f, 0.f, 0.f};
  const int wr = (w >> 1) * 64, wc = (w & 1) * 64;
  const unsigned short* aSrc = A + (rowBase + (size_t)w * 32 + l8) * K + scol + kOff;
  const unsigned short* bSrc = Bt + (colBase + (size_t)w * 32 + l8) * K + scol + kOff;

  const int NT = KL >> 6;
  auto stage = [&](int t, int buf) {
    const int kb = t << 6;
#pragma unroll
    for (int c = 0; c < 4; c++) {
      gload16(aSrc + (size_t)c * 8 * K + kb, &As[buf][(w * 4 + c) * 512]);
      gload16(bSrc + (size_t)c * 8 * K + kb, &Bs[buf][(w * 4 + c) * 512]);
    }
  };

  stage(0, 0);
  stage(1, 1);
  asm volatile("s_waitcnt vmcnt(8)" ::: "memory");
  __builtin_amdgcn_s_barrier();

  for (int t = 0; t < NT; ++t) {
    const int cur = t & 1;
    const char* asb = (const char*)As[cur];
    const char* bsb = (const char*)Bs[cur];
    __builtin_amdgcn_s_setprio(1);
#pragma unroll
    for (int ks = 0; ks < 2; ks++) {
      bf16x8 af[4], bfr[4];
      const int kbyte = ks * 64 + (hi << 4);
#pragma unroll
      for (int i = 0; i < 4; i++) {
        const int ar = wr + i * 16 + lo;
        af[i] = *(const bf16x8*)(asb + ar * 128 + (kbyte ^ ((ar & 7) << 4)));
        const int br = wc + i * 16 + lo;
        bfr[i] = *(const bf16x8*)(bsb + br * 128 + (kbyte ^ ((br & 7) << 4)));
      }
#pragma unroll
      for (int i = 0; i < 4; i++)
#pragma unroll
        for (int j = 0; j < 4; j++)
          acc[i][j] = __builtin_amdgcn_mfma_f32_16x16x32_bf16(af[i], bfr[j], acc[i][j], 0, 0, 0);
    }
    __builtin_amdgcn_s_setprio(0);
    asm volatile("s_waitcnt lgkmcnt(0)" ::: "memory");
    __builtin_amdgcn_s_barrier();  // B1: everyone done reading buf[cur]
    if (t + 2 < NT) {
      stage(t + 2, cur);
      asm volatile("s_waitcnt vmcnt(8)" ::: "memory");
    } else {
      asm volatile("s_waitcnt vmcnt(0)" ::: "memory");
    }
    __builtin_amdgcn_s_barrier();  // B2: buf[cur^1] fully staged for all waves
  }

  const size_t zOff = (size_t)blockIdx.z * M * N;
#pragma unroll
  for (int i = 0; i < 4; i++) {
#pragma unroll
    for (int r = 0; r < 4; r++) {
      const size_t row = rowBase + wr + i * 16 + hi * 4 + r;
#pragma unroll
      for (int j = 0; j < 4; j++) {
        const size_t col = colBase + wc + j * 16 + lo;
        float v = acc[i][j][r];
        if (EPI == 2) {
          ((unsigned short*)Cv)[row * N + col] = f2bf_bits(fmaxf(v + bias[col], 0.f));
        } else if (EPI == 3) {
          ((float*)Cv)[zOff + row * N + col] = v;
        } else {
          ((unsigned short*)Cv)[row * N + col] = f2bf_bits(v);
        }
      }
    }
  }
}

// ---------------- flash attention: grid 512 x 512 threads, XCD-L2 clustering.
// QBLK=128 via 8 waves x 16 q-rows (was 4 waves x 32), KVBLK=128 (16 iters).
// Same sync template as R15 (one __syncthreads per iter, dbuf Ks/Vt); only the
// wave->work mapping changed: 16 waves/CU (4/SIMD) instead of 8 (2/SIMD).
__global__ __launch_bounds__(512) void attn_k(const unsigned short* __restrict__ Q,
                                              const unsigned short* __restrict__ K,
                                              const unsigned short* __restrict__ V,
                                              unsigned short* __restrict__ O) {
  __shared__ __align__(16) unsigned short Ks[2][128 * 64];
  __shared__ __align__(16) unsigned short Vt[2][64 * 128];  // Vt[d][kv] (swizzled)
  const int tid = threadIdx.x, lane = tid & 63, w = tid >> 6;  // w in 0..7
  const int lo = lane & 15, hi = lane >> 4;
  const int l8 = lane >> 3, l7 = lane & 7;
  const int scol = ((l7 ^ l8) << 3);
  // XCD-L2 clustering: xcd = b%8 fixed per (h,n) group of 4; qt = b>>5 in [0,16)
  const int b = blockIdx.x;
  const int qt = b >> 5;
  const int hn = (b & 7) + 8 * ((b >> 3) & 3);
  const int h = hn & 15, n = hn >> 4;
  const size_t tRow0 = (size_t)n * 2048;
  const int colBase = h * 64;
  const int LD = 3072;
  const float SC = 0.125f * 1.44269504f;  // (1/sqrt(64)) * log2(e)

  // Q fragments: q-row = qt*128 + w*16 + lo (16 rows per wave)
  const unsigned short* qrow = Q + (tRow0 + qt * 128 + w * 16 + lo) * LD + colBase;
  const bf16x8 qf0 = *(const bf16x8*)(qrow + hi * 8);
  const bf16x8 qf1 = *(const bf16x8*)(qrow + 32 + hi * 8);
  float m2 = -1e30f, l_r = 0.f;  // per-lane, q = w*16 + lo
  f32x4 oacc[4];
#pragma unroll
  for (int d = 0; d < 4; d++) oacc[d] = (f32x4){0.f, 0.f, 0.f, 0.f};

  // V staging: 512 threads = 128 kv rows x 4 d-groups of 16
  const int vkv = tid & 127, vdg = tid >> 7;  // vdg in 0..3
  const unsigned short* vbase = V + (tRow0 + vkv) * LD + colBase + vdg * 16;
  // K staging: wave w owns rows w*16 .. w*16+15 (2 chunks of 8)
  const unsigned short* kbase = K + (tRow0 + (size_t)w * 16 + l8) * LD + colBase + scol;

  // conflict-free b16 scatter into Vt[d][kv] (row stride 256B), swizzle j<<4
  auto vwrite = [&](char* vt, u16x8 a0, u16x8 a1) {
#pragma unroll
    for (int j = 0; j < 8; j++) {
      const int d0 = vdg * 16 + j;
      const int sw = ((vkv * 2) ^ (j << 4));
      *(unsigned short*)(vt + d0 * 256 + sw) = a0[j];
      *(unsigned short*)(vt + (d0 + 8) * 256 + sw) = a1[j];
    }
  };

  // ---- prologue: stage tile 0 into buffer 0
  u16x8 v0 = *(const u16x8*)(vbase);
  u16x8 v1 = *(const u16x8*)(vbase + 8);
#pragma unroll
  for (int c = 0; c < 2; c++)
    gload16(kbase + (size_t)c * 8 * LD, &Ks[0][(w * 2 + c) * 512]);
  vwrite((char*)Vt[0], v0, v1);
  __syncthreads();

  for (int t = 0; t < 16; ++t) {
    const int cur = t & 1;
    // ---- issue next-tile loads early (hide under compute)
    if (t < 15) {
      const unsigned short* vs = vbase + (size_t)(t + 1) * 128 * LD;
      v0 = *(const u16x8*)(vs);
      v1 = *(const u16x8*)(vs + 8);
#pragma unroll
      for (int c = 0; c < 2; c++)
        gload16(kbase + ((size_t)(t + 1) * 128 + c * 8) * LD, &Ks[cur ^ 1][(w * 2 + c) * 512]);
    }
    // ---- swapped QK^T from Ks[cur]: s[f][r] = P[kv=f*16+hi*4+r][q]
    f32x4 s[8];
    const char* ksb = (const char*)Ks[cur];
    __builtin_amdgcn_s_setprio(1);
#pragma unroll
    for (int f = 0; f < 8; f++) {
      const int kr = f * 16 + lo;
      const bf16x8 b0 = *(const bf16x8*)(ksb + kr * 128 + ((hi * 16) ^ ((kr & 7) << 4)));
      const bf16x8 b1 = *(const bf16x8*)(ksb + kr * 128 + ((64 + hi * 16) ^ ((kr & 7) << 4)));
      s[f] = __builtin_amdgcn_mfma_f32_16x16x32_bf16(b0, qf0, (f32x4){0.f, 0.f, 0.f, 0.f}, 0, 0, 0);
      s[f] = __builtin_amdgcn_mfma_f32_16x16x32_bf16(b1, qf1, s[f], 0, 0, 0);
    }
    __builtin_amdgcn_s_setprio(0);
    // ---- softmax, lane-local for q (32 kv values per lane)
    float mx = -1e30f;
#pragma unroll
    for (int f = 0; f < 8; f++)
      mx = fmaxf(mx, fmaxf(fmaxf(s[f][0], s[f][1]), fmaxf(s[f][2], s[f][3])));
    mx = red16_max(mx);
    mx = red32_max(mx);
    const float mx2v = mx * SC;
    if (__any(mx2v > m2 + 8.f)) {  // defer-max (T13)
      const float mn = fmaxf(m2, mx2v);
      const float al = exp2_amd(m2 - mn);
      l_r *= al;
      m2 = mn;
#pragma unroll
      for (int r = 0; r < 4; r++) {
        const float alr = __shfl(al, hi * 4 + r);
#pragma unroll
        for (int d = 0; d < 4; d++) oacc[d][r] *= alr;
      }
    }
    unsigned W2[8][2];
    float lsum = 0.f;
#pragma unroll
    for (int f = 0; f < 8; f++) {
      float p0 = exp2_amd(fmaf(s[f][0], SC, -m2));
      float p1 = exp2_amd(fmaf(s[f][1], SC, -m2));
      float p2 = exp2_amd(fmaf(s[f][2], SC, -m2));
      float p3 = exp2_amd(fmaf(s[f][3], SC, -m2));
      lsum += (p0 + p1) + (p2 + p3);
      W2[f][0] = cvt_pk_bf16(p0, p1);
      W2[f][1] = cvt_pk_bf16(p2, p3);
    }
    l_r += lsum;
    // ---- redistribute P to A-fragment layout + PV
    __builtin_amdgcn_s_setprio(1);
#pragma unroll
    for (int ks = 0; ks < 4; ks++) {
      unsigned wa[2], wb[2];
#pragma unroll
      for (int hh = 0; hh < 2; hh++) {
        unsigned X = W2[ks * 2][hh], Y = W2[ks * 2 + 1][hh];
        asm("v_permlane32_swap_b32 %0, %1" : "+v"(X), "+v"(Y));
        const unsigned Bx = __shfl_xor((int)Y, 16);
        const unsigned Ax = __shfl_xor((int)X, 16);
        wa[hh] = (hi & 1) ? Bx : X;
        wb[hh] = (hi & 1) ? Y : Ax;
      }
      union { unsigned u[4]; bf16x8 v; } apu;
      apu.u[0] = wa[0]; apu.u[1] = wa[1]; apu.u[2] = wb[0]; apu.u[3] = wb[1];
      const int kbyte = ks * 64 + (hi << 4);
#pragma unroll
      for (int d = 0; d < 4; d++) {
        const int dr = d * 16 + lo;
        const bf16x8 bv = *(const bf16x8*)((const char*)Vt[cur] + dr * 256 + (kbyte ^ ((dr & 7) << 4)));
        oacc[d] = __builtin_amdgcn_mfma_f32_16x16x32_bf16(apu.v, bv, oacc[d], 0, 0, 0);
      }
    }
    __builtin_amdgcn_s_setprio(0);
    // ---- write next V tile into the other buffer (reg staging arrived by now)
    if (t < 15) vwrite((char*)Vt[cur ^ 1], v0, v1);
    __syncthreads();  // staging of next tile complete; cur reads done
  }
  // ---- epilogue: reduce l across hi-groups (q), store
  {
    const float l = red32_sum(red16_sum(l_r));
    const float inv = 1.f / l;
#pragma unroll
    for (int r = 0; r < 4; r++) {
      const float invr = __shfl(inv, hi * 4 + r);
      const size_t row = tRow0 + qt * 128 + w * 16 + hi * 4 + r;
#pragma unroll
      for (int d = 0; d < 4; d++)
        O[row * 1024 + colBase + d * 16 + lo] = f2bf_bits(oacc[d][r] * invr);
    }
  }
}

extern "C" void kernel_launch(void* const* d_in, const int* in_sizes, int n_in,
                              void* d_out, int out_size, void* d_ws, size_t ws_size,
                              hipStream_t stream) {
  (void)in_sizes; (void)n_in; (void)out_size; (void)ws_size;
  const float* x   = (const float*)d_in[0];
  const float* w_q = (const float*)d_in[2];
  const float* w_k = (const float*)d_in[3];
  const float* w_v = (const float*)d_in[4];
  const float* w_0 = (const float*)d_in[5];
  const float* b_0 = (const float*)d_in[6];
  const float* w_1 = (const float*)d_in[7];
  const float* b_1 = (const float*)d_in[8];
  const float* w_2 = (const float*)d_in[9];
  const float* b_2 = (const float*)d_in[10];
  const float* g_1 = (const float*)d_in[11];
  const float* be_1 = (const float*)d_in[12];
  const float* g_2 = (const float*)d_in[13];
  const float* be_2 = (const float*)d_in[14];

  char* ws = (char*)d_ws;
  size_t off = 0;
  auto alloc = [&](size_t bytes) {
    void* p = ws + off;
    off += (bytes + 255) & ~(size_t)255;
    return p;
  };
  const size_t MB = 1024 * 1024;
  unsigned short* wt_q = (unsigned short*)alloc(2 * MB);
  unsigned short* wt_k = (unsigned short*)alloc(2 * MB);
  unsigned short* wt_v = (unsigned short*)alloc(2 * MB);
  unsigned short* wt_0 = (unsigned short*)alloc(2 * MB);
  unsigned short* wt_1 = (unsigned short*)alloc(8 * MB);   // [4096][1024]
  unsigned short* wt_2 = (unsigned short*)alloc(8 * MB);   // [1024][4096]
  unsigned short* xn   = (unsigned short*)alloc(8 * MB);   // [4096][1024]
  unsigned short* qkv  = (unsigned short*)alloc(24 * MB);  // [4096][3072]
  unsigned short* aO   = (unsigned short*)alloc(8 * MB);
  float*          x1f  = (float*)alloc(16 * MB);           // [4096][1024] f32
  unsigned short* ff1  = (unsigned short*)alloc(32 * MB);  // [4096][4096]
  // scratch reuse (regions dead at time of use):
  float* w0part  = (float*)ff1;   // 2 x 16MB f32 W0 partials (ff1 dead until FF1)
  float* ff2part = (float*)qkv;   // 2 x 16MB f32 FF2 partials (qkv+aO dead by FF2)

  // fused: 6 weight transposes + LN1 in one dispatch
  prep_k<<<16384, 256, 0, stream>>>(w_q, w_k, w_v, w_0, w_1, w_2,
                                    wt_q, wt_k, wt_v, wt_0, wt_1, wt_2,
                                    x, g_1, be_1, xn);
  // fused QKV projection: [4096][1024] @ [3072][1024]^T -> [4096][3072]
  gemm_bt<0><<<dim3(24, 32), 256, 0, stream>>>(xn, wt_q, nullptr, nullptr, qkv, 4096, 3072, 1024, 1024);
  // attention (Q/K/V columns of the fused buffer, row stride 3072)
  attn_k<<<512, 512, 0, stream>>>(qkv, qkv + 1024, qkv + 2048, aO);
  // W0 split-K=2 -> f32 partials (into ff1 scratch), then fused reduce+residual+LN2
  gemm_bt<3><<<dim3(8, 32, 2), 256, 0, stream>>>(aO, wt_0, nullptr, nullptr, w0part, 4096, 1024, 1024, 512);
  w0red_ln<<<4096, 256, 0, stream>>>(w0part, b_0, x, g_2, be_2, x1f, xn);
  // FF1 + relu (overwrites w0part scratch)
  gemm_bt<2><<<dim3(32, 32), 256, 0, stream>>>(xn, wt_1, b_1, nullptr, ff1, 4096, 4096, 1024, 1024);
  // FF2 split-K=2 -> f32 partials, then fused reduce (+bias +residual) -> out f32
  gemm_bt<3><<<dim3(8, 32, 2), 256, 0, stream>>>(ff1, wt_2, nullptr, nullptr, ff2part, 4096, 1024, 4096, 2048);
  ff2red<<<2048, 256, 0, stream>>>(ff2part, b_2, x1f, (float*)d_out);
}

// Round 18
// 244.144 us; speedup vs baseline: 1.0202x; 1.0011x over previous
//
#include <hip/hip_runtime.h>

typedef __bf16 bf16x8 __attribute__((ext_vector_type(8)));
typedef float f32x4 __attribute__((ext_vector_type(4)));
typedef unsigned short u16x8 __attribute__((ext_vector_type(8)));
typedef unsigned short u16x4 __attribute__((ext_vector_type(4)));

__device__ __forceinline__ unsigned short f2bf_bits(float f) {
  unsigned u = __float_as_uint(f);
  return (unsigned short)((u + 0x7FFFu + ((u >> 16) & 1u)) >> 16);
}

__device__ __forceinline__ float exp2_amd(float x) {
  return __builtin_amdgcn_exp2f(x);
}

__device__ __forceinline__ unsigned cvt_pk_bf16(float a, float b) {
  unsigned r;
  asm("v_cvt_pk_bf16_f32 %0, %1, %2" : "=v"(r) : "v"(a), "v"(b));
  return r;
}

// xor16 / xor32 reductions on the VALU pipe (permlane swap) instead of ds_swizzle
__device__ __forceinline__ float red16_max(float x) {
  unsigned a = __float_as_uint(x), b = a;
  asm("v_permlane16_swap_b32 %0, %1" : "+v"(a), "+v"(b));
  return fmaxf(__uint_as_float(a), __uint_as_float(b));
}
__device__ __forceinline__ float red32_max(float x) {
  unsigned a = __float_as_uint(x), b = a;
  asm("v_permlane32_swap_b32 %0, %1" : "+v"(a), "+v"(b));
  return fmaxf(__uint_as_float(a), __uint_as_float(b));
}
__device__ __forceinline__ float red16_sum(float x) {
  unsigned a = __float_as_uint(x), b = a;
  asm("v_permlane16_swap_b32 %0, %1" : "+v"(a), "+v"(b));
  return __uint_as_float(a) + __uint_as_float(b);
}
__device__ __forceinline__ float red32_sum(float x) {
  unsigned a = __float_as_uint(x), b = a;
  asm("v_permlane32_swap_b32 %0, %1" : "+v"(a), "+v"(b));
  return __uint_as_float(a) + __uint_as_float(b);
}

__device__ __forceinline__ void gload16(const void* g, void* l) {
  __builtin_amdgcn_global_load_lds(
      (const __attribute__((address_space(1))) unsigned int*)g,
      (__attribute__((address_space(3))) unsigned int*)l, 16, 0, 0);
}

// ---------------- fused prep: 6 weight transposes + LN1, one dispatch.
// blocks [0,12288): wconv tiles; blocks [12288,16384): LN1 rows.
__global__ __launch_bounds__(256) void prep_k(
    const float* __restrict__ s0, const float* __restrict__ s1,
    const float* __restrict__ s2, const float* __restrict__ s3,
    const float* __restrict__ s4, const float* __restrict__ s5,
    unsigned short* __restrict__ d0, unsigned short* __restrict__ d1,
    unsigned short* __restrict__ d2, unsigned short* __restrict__ d3,
    unsigned short* __restrict__ d4, unsigned short* __restrict__ d5,
    const float* __restrict__ x, const float* __restrict__ g1,
    const float* __restrict__ be1, unsigned short* __restrict__ xn) {
  const int t = blockIdx.x;
  const int tid = threadIdx.x;
  if (t >= 12288) {
    // ---- LN1 row
    const int row = t - 12288;
    const float4 v = ((const float4*)(x + (size_t)row * 1024))[tid];
    float s = v.x + v.y + v.z + v.w;
    float s2 = v.x * v.x + v.y * v.y + v.z * v.z + v.w * v.w;
#pragma unroll
    for (int m = 1; m < 64; m <<= 1) {
      s += __shfl_xor(s, m);
      s2 += __shfl_xor(s2, m);
    }
    __shared__ float red[8];
    const int w = tid >> 6;
    if ((tid & 63) == 0) { red[w] = s; red[4 + w] = s2; }
    __syncthreads();
    s = red[0] + red[1] + red[2] + red[3];
    s2 = red[4] + red[5] + red[6] + red[7];
    const float mu = s * (1.f / 1024.f);
    const float rs_ = rsqrtf(s2 * (1.f / 1024.f) - mu * mu + 1e-5f);
    const float4 gg = ((const float4*)g1)[tid];
    const float4 bb = ((const float4*)be1)[tid];
    u16x4 pack;
    pack.x = f2bf_bits((v.x - mu) * rs_ * gg.x + bb.x);
    pack.y = f2bf_bits((v.y - mu) * rs_ * gg.y + bb.y);
    pack.z = f2bf_bits((v.z - mu) * rs_ * gg.z + bb.z);
    pack.w = f2bf_bits((v.w - mu) * rs_ * gg.w + bb.w);
    *(u16x4*)(xn + (size_t)row * 1024 + tid * 4) = pack;
    return;
  }
  // ---- weight convert+transpose tile
  const float* src;
  unsigned short* dst;
  int R, C, bx, by;
  if (t < 4096) {
    const int i = t >> 10, id = t & 1023;
    src = i == 0 ? s0 : i == 1 ? s1 : i == 2 ? s2 : s3;
    dst = i == 0 ? d0 : i == 1 ? d1 : i == 2 ? d2 : d3;
    R = 1024; C = 1024; bx = id & 31; by = id >> 5;
  } else if (t < 8192) {
    const int id = t - 4096;
    src = s4; dst = d4; R = 1024; C = 4096; bx = id & 127; by = id >> 7;
  } else {
    const int id = t - 8192;
    src = s5; dst = d5; R = 4096; C = 1024; bx = id & 31; by = id >> 5;
  }
  __shared__ float tile[32][33];
  const int tx = tid & 31, ty = tid >> 5;
  const size_t c0 = (size_t)bx * 32, r0 = (size_t)by * 32;
#pragma unroll
  for (int i = 0; i < 4; i++)
    tile[ty + i * 8][tx] = src[(r0 + ty + i * 8) * C + c0 + tx];
  __syncthreads();
#pragma unroll
  for (int i = 0; i < 4; i++) {
    int c = ty + i * 8;
    dst[(c0 + c) * R + r0 + tx] = f2bf_bits(tile[tx][c]);
  }
}

// ---------------- W0 split-K(f32) reduce + residual + LN2 fused:
// x1 = p0 + p1 + b0 + x  (write f32);  xn = LN(x1; g2, be2)  (write bf16)
__global__ __launch_bounds__(256) void w0red_ln(const float* __restrict__ p,
                                                const float* __restrict__ b0,
                                                const float* __restrict__ x,
                                                const float* __restrict__ g,
                                                const float* __restrict__ be,
                                                float* __restrict__ x1f,
                                                unsigned short* __restrict__ xn) {
  const int row = blockIdx.x, tid = threadIdx.x;
  const size_t base = (size_t)row * 1024 + tid * 4;
  const float4 xv = *(const float4*)(x + base);
  const float4 bb0 = ((const float4*)b0)[tid];
  const float4 p0 = *(const float4*)(p + base);
  const float4 p1 = *(const float4*)(p + 4194304 + base);
  float4 v;
  v.x = xv.x + bb0.x + p0.x + p1.x;
  v.y = xv.y + bb0.y + p0.y + p1.y;
  v.z = xv.z + bb0.z + p0.z + p1.z;
  v.w = xv.w + bb0.w + p0.w + p1.w;
  *(float4*)(x1f + base) = v;
  float s = v.x + v.y + v.z + v.w;
  float s2 = v.x * v.x + v.y * v.y + v.z * v.z + v.w * v.w;
#pragma unroll
  for (int m = 1; m < 64; m <<= 1) {
    s += __shfl_xor(s, m);
    s2 += __shfl_xor(s2, m);
  }
  __shared__ float red[8];
  const int w = tid >> 6;
  if ((tid & 63) == 0) { red[w] = s; red[4 + w] = s2; }
  __syncthreads();
  s = red[0] + red[1] + red[2] + red[3];
  s2 = red[4] + red[5] + red[6] + red[7];
  const float mu = s * (1.f / 1024.f);
  const float rs_ = rsqrtf(s2 * (1.f / 1024.f) - mu * mu + 1e-5f);
  const float4 gg = ((const float4*)g)[tid];
  const float4 bb = ((const float4*)be)[tid];
  u16x4 pack;
  pack.x = f2bf_bits((v.x - mu) * rs_ * gg.x + bb.x);
  pack.y = f2bf_bits((v.y - mu) * rs_ * gg.y + bb.y);
  pack.z = f2bf_bits((v.z - mu) * rs_ * gg.z + bb.z);
  pack.w = f2bf_bits((v.w - mu) * rs_ * gg.w + bb.w);
  *(u16x4*)(xn + base) = pack;
}

// ---------------- split-K reduce for FF2: out = p0 + p1 + bias + res (all f32)
__global__ __launch_bounds__(256) void ff2red(const float* __restrict__ p,
                                              const float* __restrict__ bias,
                                              const float* __restrict__ res,
                                              float* __restrict__ out) {
  const size_t i = ((size_t)blockIdx.x * 256 + threadIdx.x) * 8;
  const int col = (int)(i & 1023);
  const float4 b0 = *(const float4*)(bias + col);
  const float4 b1 = *(const float4*)(bias + col + 4);
  const float4 r0 = *(const float4*)(res + i);
  const float4 r1 = *(const float4*)(res + i + 4);
  const float4 p00 = *(const float4*)(p + i);
  const float4 p01 = *(const float4*)(p + i + 4);
  const float4 p10 = *(const float4*)(p + 4194304 + i);
  const float4 p11 = *(const float4*)(p + 4194304 + i + 4);
  float4 o0 = {b0.x + r0.x + p00.x + p10.x, b0.y + r0.y + p00.y + p10.y,
               b0.z + r0.z + p00.z + p10.z, b0.w + r0.w + p00.w + p10.w};
  float4 o1 = {b1.x + r1.x + p01.x + p11.x, b1.y + r1.y + p01.y + p11.y,
               b1.z + r1.z + p01.z + p11.z, b1.w + r1.w + p01.w + p11.w};
  *(float4*)(out + i) = o0;
  *(float4*)(out + i + 4) = o1;
}

// ---------------- GEMM: C[M][N] = epi(A[M][K(row stride)] @ Bt[N][K]^T ...)
// EPI 0: bf16 store. 2: +bias, relu, bf16 store. 3: f32 PARTIAL store at z-slice.
// Counted-vmcnt double-buffered pipeline (T3/T4) + XCD swizzle (T1) + setprio (T5).
template <int EPI>
__global__ __launch_bounds__(256) void gemm_bt(
    const unsigned short* __restrict__ A, const unsigned short* __restrict__ Bt,
    const float* __restrict__ bias, const float* __restrict__ res,
    void* __restrict__ Cv, int M, int N, int K, int KL) {
  __shared__ __align__(16) unsigned short As[2][128 * 64];
  __shared__ __align__(16) unsigned short Bs[2][128 * 64];
  const int tid = threadIdx.x, lane = tid & 63, w = tid >> 6;
  const int lo = lane & 15, hi = lane >> 4;
  const int l8 = lane >> 3, l7 = lane & 7;
  const int scol = ((l7 ^ l8) << 3);  // swizzled source col (elements)
  const int nwg = gridDim.x * gridDim.y;
  int bid = blockIdx.y * gridDim.x + blockIdx.x;
  if ((nwg & 7) == 0) bid = (bid & 7) * (nwg >> 3) + (bid >> 3);
  const int bx = bid % gridDim.x, by = bid / gridDim.x;
  const size_t rowBase = (size_t)by * 128;
  const size_t colBase = (size_t)bx * 128;
  const int kOff = blockIdx.z * KL;
  f32x4 acc[4][4];
#pragma unroll
  for (int i = 0; i < 4; i++)
#pragma unroll
    for (int j = 0; j < 4; j++) acc[i][j] = (f32x4){0.f, 0.f, 0.f, 0.f};
  const int wr = (w >> 1) * 64, wc = (w & 1) * 64;
  const unsigned short* aSrc = A + (rowBase + (size_t)w * 32 + l8) * K + scol + kOff;
  const unsigned short* bSrc = Bt + (colBase + (size_t)w * 32 + l8) * K + scol + kOff;

  const int NT = KL >> 6;
  auto stage = [&](int t, int buf) {
    const int kb = t << 6;
#pragma unroll
    for (int c = 0; c < 4; c++) {
      gload16(aSrc + (size_t)c * 8 * K + kb, &As[buf][(w * 4 + c) * 512]);
      gload16(bSrc + (size_t)c * 8 * K + kb, &Bs[buf][(w * 4 + c) * 512]);
    }
  };

  stage(0, 0);
  stage(1, 1);
  asm volatile("s_waitcnt vmcnt(8)" ::: "memory");
  __builtin_amdgcn_s_barrier();

  for (int t = 0; t < NT; ++t) {
    const int cur = t & 1;
    const char* asb = (const char*)As[cur];
    const char* bsb = (const char*)Bs[cur];
    __builtin_amdgcn_s_setprio(1);
#pragma unroll
    for (int ks = 0; ks < 2; ks++) {
      bf16x8 af[4], bfr[4];
      const int kbyte = ks * 64 + (hi << 4);
#pragma unroll
      for (int i = 0; i < 4; i++) {
        const int ar = wr + i * 16 + lo;
        af[i] = *(const bf16x8*)(asb + ar * 128 + (kbyte ^ ((ar & 7) << 4)));
        const int br = wc + i * 16 + lo;
        bfr[i] = *(const bf16x8*)(bsb + br * 128 + (kbyte ^ ((br & 7) << 4)));
      }
#pragma unroll
      for (int i = 0; i < 4; i++)
#pragma unroll
        for (int j = 0; j < 4; j++)
          acc[i][j] = __builtin_amdgcn_mfma_f32_16x16x32_bf16(af[i], bfr[j], acc[i][j], 0, 0, 0);
    }
    __builtin_amdgcn_s_setprio(0);
    asm volatile("s_waitcnt lgkmcnt(0)" ::: "memory");
    __builtin_amdgcn_s_barrier();  // B1: everyone done reading buf[cur]
    if (t + 2 < NT) {
      stage(t + 2, cur);
      asm volatile("s_waitcnt vmcnt(8)" ::: "memory");
    } else {
      asm volatile("s_waitcnt vmcnt(0)" ::: "memory");
    }
    __builtin_amdgcn_s_barrier();  // B2: buf[cur^1] fully staged for all waves
  }

  const size_t zOff = (size_t)blockIdx.z * M * N;
#pragma unroll
  for (int i = 0; i < 4; i++) {
#pragma unroll
    for (int r = 0; r < 4; r++) {
      const size_t row = rowBase + wr + i * 16 + hi * 4 + r;
#pragma unroll
      for (int j = 0; j < 4; j++) {
        const size_t col = colBase + wc + j * 16 + lo;
        float v = acc[i][j][r];
        if (EPI == 2) {
          ((unsigned short*)Cv)[row * N + col] = f2bf_bits(fmaxf(v + bias[col], 0.f));
        } else if (EPI == 3) {
          ((float*)Cv)[zOff + row * N + col] = v;
        } else {
          ((unsigned short*)Cv)[row * N + col] = f2bf_bits(v);
        }
      }
    }
  }
}

// ---------------- flash attention: grid 512 x 512 threads, XCD-L2 clustering.
// QBLK=128 via 8 waves x 16 q-rows, KVBLK=128 (16 iters).
// One __syncthreads per iter, double-buffered Ks/Vt; 16 waves/CU (4/SIMD).
__global__ __launch_bounds__(512) void attn_k(const unsigned short* __restrict__ Q,
                                              const unsigned short* __restrict__ K,
                                              const unsigned short* __restrict__ V,
                                              unsigned short* __restrict__ O) {
  __shared__ __align__(16) unsigned short Ks[2][128 * 64];
  __shared__ __align__(16) unsigned short Vt[2][64 * 128];  // Vt[d][kv] (swizzled)
  const int tid = threadIdx.x, lane = tid & 63, w = tid >> 6;  // w in 0..7
  const int lo = lane & 15, hi = lane >> 4;
  const int l8 = lane >> 3, l7 = lane & 7;
  const int scol = ((l7 ^ l8) << 3);
  // XCD-L2 clustering: xcd = b%8 fixed per (h,n) group of 4; qt = b>>5 in [0,16)
  const int b = blockIdx.x;
  const int qt = b >> 5;
  const int hn = (b & 7) + 8 * ((b >> 3) & 3);
  const int h = hn & 15, n = hn >> 4;
  const size_t tRow0 = (size_t)n * 2048;
  const int colBase = h * 64;
  const int LD = 3072;
  const float SC = 0.125f * 1.44269504f;  // (1/sqrt(64)) * log2(e)

  // Q fragments: q-row = qt*128 + w*16 + lo (16 rows per wave)
  const unsigned short* qrow = Q + (tRow0 + qt * 128 + w * 16 + lo) * LD + colBase;
  const bf16x8 qf0 = *(const bf16x8*)(qrow + hi * 8);
  const bf16x8 qf1 = *(const bf16x8*)(qrow + 32 + hi * 8);
  float m2 = -1e30f, l_r = 0.f;  // per-lane, q = w*16 + lo
  f32x4 oacc[4];
#pragma unroll
  for (int d = 0; d < 4; d++) oacc[d] = (f32x4){0.f, 0.f, 0.f, 0.f};

  // V staging: 512 threads = 128 kv rows x 4 d-groups of 16
  const int vkv = tid & 127, vdg = tid >> 7;  // vdg in 0..3
  const unsigned short* vbase = V + (tRow0 + vkv) * LD + colBase + vdg * 16;
  // K staging: wave w owns rows w*16 .. w*16+15 (2 chunks of 8)
  const unsigned short* kbase = K + (tRow0 + (size_t)w * 16 + l8) * LD + colBase + scol;

  // conflict-free b16 scatter into Vt[d][kv] (row stride 256B), swizzle j<<4
  auto vwrite = [&](char* vt, u16x8 a0, u16x8 a1) {
#pragma unroll
    for (int j = 0; j < 8; j++) {
      const int d0 = vdg * 16 + j;
      const int sw = ((vkv * 2) ^ (j << 4));
      *(unsigned short*)(vt + d0 * 256 + sw) = a0[j];
      *(unsigned short*)(vt + (d0 + 8) * 256 + sw) = a1[j];
    }
  };

  // ---- prologue: stage tile 0 into buffer 0
  u16x8 v0 = *(const u16x8*)(vbase);
  u16x8 v1 = *(const u16x8*)(vbase + 8);
#pragma unroll
  for (int c = 0; c < 2; c++)
    gload16(kbase + (size_t)c * 8 * LD, &Ks[0][(w * 2 + c) * 512]);
  vwrite((char*)Vt[0], v0, v1);
  __syncthreads();

  for (int t = 0; t < 16; ++t) {
    const int cur = t & 1;
    // ---- issue next-tile loads early (hide under compute)
    if (t < 15) {
      const unsigned short* vs = vbase + (size_t)(t + 1) * 128 * LD;
      v0 = *(const u16x8*)(vs);
      v1 = *(const u16x8*)(vs + 8);
#pragma unroll
      for (int c = 0; c < 2; c++)
        gload16(kbase + ((size_t)(t + 1) * 128 + c * 8) * LD, &Ks[cur ^ 1][(w * 2 + c) * 512]);
    }
    // ---- swapped QK^T from Ks[cur]: s[f][r] = P[kv=f*16+hi*4+r][q]
    f32x4 s[8];
    const char* ksb = (const char*)Ks[cur];
    __builtin_amdgcn_s_setprio(1);
#pragma unroll
    for (int f = 0; f < 8; f++) {
      const int kr = f * 16 + lo;
      const bf16x8 b0 = *(const bf16x8*)(ksb + kr * 128 + ((hi * 16) ^ ((kr & 7) << 4)));
      const bf16x8 b1 = *(const bf16x8*)(ksb + kr * 128 + ((64 + hi * 16) ^ ((kr & 7) << 4)));
      s[f] = __builtin_amdgcn_mfma_f32_16x16x32_bf16(b0, qf0, (f32x4){0.f, 0.f, 0.f, 0.f}, 0, 0, 0);
      s[f] = __builtin_amdgcn_mfma_f32_16x16x32_bf16(b1, qf1, s[f], 0, 0, 0);
    }
    __builtin_amdgcn_s_setprio(0);
    // ---- softmax, lane-local for q (32 kv values per lane)
    float mx = -1e30f;
#pragma unroll
    for (int f = 0; f < 8; f++)
      mx = fmaxf(mx, fmaxf(fmaxf(s[f][0], s[f][1]), fmaxf(s[f][2], s[f][3])));
    mx = red16_max(mx);
    mx = red32_max(mx);
    const float mx2v = mx * SC;
    if (__any(mx2v > m2 + 8.f)) {  // defer-max (T13)
      const float mn = fmaxf(m2, mx2v);
      const float al = exp2_amd(m2 - mn);
      l_r *= al;
      m2 = mn;
#pragma unroll
      for (int r = 0; r < 4; r++) {
        const float alr = __shfl(al, hi * 4 + r);
#pragma unroll
        for (int d = 0; d < 4; d++) oacc[d][r] *= alr;
      }
    }
    unsigned W2[8][2];
    float lsum = 0.f;
#pragma unroll
    for (int f = 0; f < 8; f++) {
      float p0 = exp2_amd(fmaf(s[f][0], SC, -m2));
      float p1 = exp2_amd(fmaf(s[f][1], SC, -m2));
      float p2 = exp2_amd(fmaf(s[f][2], SC, -m2));
      float p3 = exp2_amd(fmaf(s[f][3], SC, -m2));
      lsum += (p0 + p1) + (p2 + p3);
      W2[f][0] = cvt_pk_bf16(p0, p1);
      W2[f][1] = cvt_pk_bf16(p2, p3);
    }
    l_r += lsum;
    // ---- redistribute P to A-fragment layout + PV
    __builtin_amdgcn_s_setprio(1);
#pragma unroll
    for (int ks = 0; ks < 4; ks++) {
      unsigned wa[2], wb[2];
#pragma unroll
      for (int hh = 0; hh < 2; hh++) {
        unsigned X = W2[ks * 2][hh], Y = W2[ks * 2 + 1][hh];
        asm("v_permlane32_swap_b32 %0, %1" : "+v"(X), "+v"(Y));
        const unsigned Bx = __shfl_xor((int)Y, 16);
        const unsigned Ax = __shfl_xor((int)X, 16);
        wa[hh] = (hi & 1) ? Bx : X;
        wb[hh] = (hi & 1) ? Y : Ax;
      }
      union { unsigned u[4]; bf16x8 v; } apu;
      apu.u[0] = wa[0]; apu.u[1] = wa[1]; apu.u[2] = wb[0]; apu.u[3] = wb[1];
      const int kbyte = ks * 64 + (hi << 4);
#pragma unroll
      for (int d = 0; d < 4; d++) {
        const int dr = d * 16 + lo;
        const bf16x8 bv = *(const bf16x8*)((const char*)Vt[cur] + dr * 256 + (kbyte ^ ((dr & 7) << 4)));
        oacc[d] = __builtin_amdgcn_mfma_f32_16x16x32_bf16(apu.v, bv, oacc[d], 0, 0, 0);
      }
    }
    __builtin_amdgcn_s_setprio(0);
    // ---- write next V tile into the other buffer (reg staging arrived by now)
    if (t < 15) vwrite((char*)Vt[cur ^ 1], v0, v1);
    __syncthreads();  // staging of next tile complete; cur reads done
  }
  // ---- epilogue: reduce l across hi-groups (q), store
  {
    const float l = red32_sum(red16_sum(l_r));
    const float inv = 1.f / l;
#pragma unroll
    for (int r = 0; r < 4; r++) {
      const float invr = __shfl(inv, hi * 4 + r);
      const size_t row = tRow0 + qt * 128 + w * 16 + hi * 4 + r;
#pragma unroll
      for (int d = 0; d < 4; d++)
        O[row * 1024 + colBase + d * 16 + lo] = f2bf_bits(oacc[d][r] * invr);
    }
  }
}

extern "C" void kernel_launch(void* const* d_in, const int* in_sizes, int n_in,
                              void* d_out, int out_size, void* d_ws, size_t ws_size,
                              hipStream_t stream) {
  (void)in_sizes; (void)n_in; (void)out_size; (void)ws_size;
  const float* x   = (const float*)d_in[0];
  const float* w_q = (const float*)d_in[2];
  const float* w_k = (const float*)d_in[3];
  const float* w_v = (const float*)d_in[4];
  const float* w_0 = (const float*)d_in[5];
  const float* b_0 = (const float*)d_in[6];
  const float* w_1 = (const float*)d_in[7];
  const float* b_1 = (const float*)d_in[8];
  const float* w_2 = (const float*)d_in[9];
  const float* b_2 = (const float*)d_in[10];
  const float* g_1 = (const float*)d_in[11];
  const float* be_1 = (const float*)d_in[12];
  const float* g_2 = (const float*)d_in[13];
  const float* be_2 = (const float*)d_in[14];

  char* ws = (char*)d_ws;
  size_t off = 0;
  auto alloc = [&](size_t bytes) {
    void* p = ws + off;
    off += (bytes + 255) & ~(size_t)255;
    return p;
  };
  const size_t MB = 1024 * 1024;
  unsigned short* wt_q = (unsigned short*)alloc(2 * MB);
  unsigned short* wt_k = (unsigned short*)alloc(2 * MB);
  unsigned short* wt_v = (unsigned short*)alloc(2 * MB);
  unsigned short* wt_0 = (unsigned short*)alloc(2 * MB);
  unsigned short* wt_1 = (unsigned short*)alloc(8 * MB);   // [4096][1024]
  unsigned short* wt_2 = (unsigned short*)alloc(8 * MB);   // [1024][4096]
  unsigned short* xn   = (unsigned short*)alloc(8 * MB);   // [4096][1024]
  unsigned short* qkv  = (unsigned short*)alloc(24 * MB);  // [4096][3072]
  unsigned short* aO   = (unsigned short*)alloc(8 * MB);
  float*          x1f  = (float*)alloc(16 * MB);           // [4096][1024] f32
  unsigned short* ff1  = (unsigned short*)alloc(32 * MB);  // [4096][4096]
  // scratch reuse (regions dead at time of use):
  float* w0part  = (float*)ff1;   // 2 x 16MB f32 W0 partials (ff1 dead until FF1)
  float* ff2part = (float*)qkv;   // 2 x 16MB f32 FF2 partials (qkv+aO dead by FF2)

  // fused: 6 weight transposes + LN1 in one dispatch
  prep_k<<<16384, 256, 0, stream>>>(w_q, w_k, w_v, w_0, w_1, w_2,
                                    wt_q, wt_k, wt_v, wt_0, wt_1, wt_2,
                                    x, g_1, be_1, xn);
  // fused QKV projection: [4096][1024] @ [3072][1024]^T -> [4096][3072]
  gemm_bt<0><<<dim3(24, 32), 256, 0, stream>>>(xn, wt_q, nullptr, nullptr, qkv, 4096, 3072, 1024, 1024);
  // attention (Q/K/V columns of the fused buffer, row stride 3072)
  attn_k<<<512, 512, 0, stream>>>(qkv, qkv + 1024, qkv + 2048, aO);
  // W0 split-K=2 -> f32 partials (into ff1 scratch), then fused reduce+residual+LN2
  gemm_bt<3><<<dim3(8, 32, 2), 256, 0, stream>>>(aO, wt_0, nullptr, nullptr, w0part, 4096, 1024, 1024, 512);
  w0red_ln<<<4096, 256, 0, stream>>>(w0part, b_0, x, g_2, be_2, x1f, xn);
  // FF1 + relu (overwrites w0part scratch)
  gemm_bt<2><<<dim3(32, 32), 256, 0, stream>>>(xn, wt_1, b_1, nullptr, ff1, 4096, 4096, 1024, 1024);
  // FF2 split-K=2 -> f32 partials, then fused reduce (+bias +residual) -> out f32
  gemm_bt<3><<<dim3(8, 32, 2), 256, 0, stream>>>(ff1, wt_2, nullptr, nullptr, ff2part, 4096, 1024, 4096, 2048);
  ff2red<<<2048, 256, 0, stream>>>(ff2part, b_2, x1f, (float*)d_out);
}